// Round 11
// baseline (10446.850 us; speedup 1.0000x reference)
//
#include <hip/hip_runtime.h>
#include <hip/hip_bf16.h>

// R11: ZERO cross-block communication. 8 blocks = 1 batch each, 1024 threads
// (16 waves). Whole recurrence is block-local: LDS-only barriers, no global
// sync of any kind (R3-R10 proved the cross-block RT is a ~6us invariant).
// z-GEMM K extended to 416: kt12 carries [x0..x4, 1.0] so x-part and bias
// ride the MFMA. Weights live in VGPRs (208/wave). W2 via padded-N MFMA.

#define NB 8
#define NT 128
#define NS 128
#define NSTEP 127
#define TPRED 4
#define TOUT 123

typedef __attribute__((ext_vector_type(4))) float f32x4;
typedef __attribute__((ext_vector_type(8))) short s16x8;

// workspace layout (bytes)
#define WS_WTC 0                          // bf16 [512][416] col''=q*64+g*16+h; K=[hb,h,ha,x,1,pad]
#define WS_WT1 (512*416*2)                // bf16 [128][128] [out_col][k]
#define WS_WT2 (WS_WT1 + 128*128*2)       // bf16 [16][128]  [out_col(pad 3->16)][k]

// LDS-only barrier: orders DS ops, does NOT drain vmcnt (global stores float)
#define BARRIER() do { \
    __builtin_amdgcn_sched_barrier(0); \
    asm volatile("s_waitcnt lgkmcnt(0)" ::: "memory"); \
    __builtin_amdgcn_s_barrier(); \
    __builtin_amdgcn_sched_barrier(0); \
} while (0)

__device__ __forceinline__ unsigned swz(unsigned off) {
    return off ^ (((off >> 8) & 7u) << 4);
}

__global__ void init_weights(const float* __restrict__ Wc, const float* __restrict__ bc,
                             const float* __restrict__ W1, const float* __restrict__ W2,
                             __hip_bfloat16* __restrict__ WTc, __hip_bfloat16* __restrict__ WT1,
                             __hip_bfloat16* __restrict__ WT2)
{
    int i = blockIdx.x * blockDim.x + threadIdx.x;
    if (i < 512*416) {
        int cpp = i / 416, k = i % 416;
        int q = cpp >> 6, rem = cpp & 63, g = rem >> 4, h = rem & 15;
        int oc = g*128 + 16*q + h;     // original W_cell column
        float v;
        if      (k < 128) v = Wc[(261 + k)*512 + oc];          // h_before
        else if (k < 256) v = Wc[(5 + (k - 128))*512 + oc];    // h
        else if (k < 384) v = Wc[(133 + (k - 256))*512 + oc];  // h_after
        else if (k < 389) v = Wc[(k - 384)*512 + oc];          // x0..x4
        else if (k == 389) v = bc[oc];                          // bias (x1.0)
        else v = 0.f;
        WTc[cpp*416 + k] = __float2bfloat16(v);
    } else if (i < 512*416 + 128*128) {
        int qq = i - 512*416;
        int nn = qq >> 7, k = qq & 127;
        WT1[nn*128 + k] = __float2bfloat16(W1[k*128 + nn]);
    } else if (i < 512*416 + 128*128 + 16*128) {
        int qq = i - 512*416 - 128*128;
        int cc = qq >> 7, k = qq & 127;
        WT2[cc*128 + k] = __float2bfloat16(cc < 3 ? W2[k*3 + cc] : 0.f);
    }
}

__global__ __launch_bounds__(1024, 1) void lstm_persist(
    const float* __restrict__ input, const float* __restrict__ b1v,
    const float* __restrict__ b2v, float* __restrict__ outp,
    const __hip_bfloat16* __restrict__ WTc, const __hip_bfloat16* __restrict__ WT1,
    const __hip_bfloat16* __restrict__ WT2)
{
    __shared__ __align__(16) __hip_bfloat16 hl[2*130*128];   // dbuf; row i = h[i-1]; rows 0/129 = 0 (swz)
    __shared__ __align__(16) __hip_bfloat16 relu_l[128*128]; // swz, rows 0..127
    __shared__ __align__(16) __hip_bfloat16 xlt[2*128*40];   // [buf][row][40]: cols0-4=x,5=1.0,rest 0 (80B rows)
    __shared__ float xl[3][640];    // f32 x staging (epilogue), mod-3
    __shared__ float outl[128*3];

    const int tid  = threadIdx.x;
    const int b    = blockIdx.x;     // batch
    const int lane = tid & 63;
    const int q    = tid >> 6;       // wave 0..15
    const int qm   = q >> 3;         // M half (z-phase)
    const int qh   = q & 7;          // hid group (z-phase)
    const int mtD  = q & 7;          // M tile (W1 phase)
    const int qn   = q >> 3;         // N half (W1 phase)
    const int arow = lane & 15;
    const int kgrp = lane >> 4;

    for (int i = tid; i < 2*130*128; i += 1024) ((unsigned short*)hl)[i] = 0;
    if (tid < 128) {
        // zero xlt cols 8..39 of both buffers (cols 0..7 written per step)
        for (int c = 8; c < 40; ++c) {
            xlt[0*128*40 + tid*40 + c] = __float2bfloat16(0.f);
            xlt[1*128*40 + tid*40 + c] = __float2bfloat16(0.f);
        }
        // stage xlt[0] from x(0)
        const float* xp = input + (unsigned)(b*NT)*640 + tid*5;
        unsigned short u0 = *(unsigned short*)&(__hip_bfloat16&)(*(__hip_bfloat16[1]){__float2bfloat16(xp[0])});
        (void)u0;
        __hip_bfloat16 c0 = __float2bfloat16(xp[0]), c1 = __float2bfloat16(xp[1]),
                       c2 = __float2bfloat16(xp[2]), c3 = __float2bfloat16(xp[3]),
                       c4 = __float2bfloat16(xp[4]);
        unsigned short* xr0 = (unsigned short*)&xlt[0*128*40 + tid*40];
        xr0[0] = *(unsigned short*)&c0; xr0[1] = *(unsigned short*)&c1;
        xr0[2] = *(unsigned short*)&c2; xr0[3] = *(unsigned short*)&c3;
        xr0[4] = *(unsigned short*)&c4; xr0[5] = 0x3F80; xr0[6] = 0; xr0[7] = 0;
    }
    if (tid < 640) xl[0][tid] = input[(unsigned)(b*NT)*640 + tid];

    // ---- weights into registers ----
    s16x8 brg[4][13];
    #pragma unroll
    for (int g = 0; g < 4; ++g)
        #pragma unroll
        for (int kt = 0; kt < 13; ++kt)
            brg[g][kt] = *(const s16x8*)((const char*)WTc +
                ((unsigned)(qh*64 + g*16 + arow)*416 + kt*32 + kgrp*8)*2);
    s16x8 w1r[4][4];
    #pragma unroll
    for (int nt = 0; nt < 4; ++nt)
        #pragma unroll
        for (int kt = 0; kt < 4; ++kt)
            w1r[nt][kt] = *(const s16x8*)((const char*)WT1 +
                ((unsigned)(qn*64 + nt*16 + arow)*128 + kt*32 + kgrp*8)*2);
    s16x8 w2r[4];
    #pragma unroll
    for (int kt = 0; kt < 4; ++kt)
        w2r[kt] = *(const s16x8*)((const char*)WT2 + ((unsigned)arow*128 + kt*32 + kgrp*8)*2);
    float b1r[4];
    #pragma unroll
    for (int nt = 0; nt < 4; ++nt) b1r[nt] = b1v[qn*64 + nt*16 + arow];
    const float b2r = (arow < 3) ? b2v[arow] : 0.f;

    float cst[16];
    #pragma unroll
    for (int i = 0; i < 16; ++i) cst[i] = 0.f;

    __syncthreads();

    for (int j = 0; j <= NSTEP; ++j) {
        const int jm3 = j % 3;
        const unsigned hlb  = (unsigned)(j & 1) * 33280u;         // 130*256
        const unsigned nhlb = (unsigned)((j + 1) & 1) * 33280u;
        const unsigned xlb  = (unsigned)(j & 1) * 10240u;         // 128*80

        // ---- prefetch x(j+1) (issue early; commit at loop bottom) ----
        float xr = 0.f, p0 = 0.f, p1 = 0.f, p2 = 0.f, p3 = 0.f, p4 = 0.f;
        const bool act640 = (j < NSTEP) && (tid < 640);
        const bool act128 = (j < NSTEP) && (tid < 128);
        if (act640) xr = input[(unsigned)(b*NT + j + 1)*640 + tid];
        if (act128) {
            const float* xp = input + (unsigned)(b*NT + j + 1)*640 + tid*5;
            p0 = xp[0]; p1 = xp[1]; p2 = xp[2]; p3 = xp[3]; p4 = xp[4];
        }

        BARRIER();  // B1: hl[cur] (h(j)) complete, xlt[cur]/xl[jm3] staged

        // ---- z-phase: M=128 N=512 K=416 + gates -> h(j+1) ----
        if (j < NSTEP) {
            #pragma unroll
            for (int mt = 0; mt < 4; ++mt) {
                f32x4 a0 = {0.f,0.f,0.f,0.f}, a1 = a0, a2 = a0, a3 = a0;
                const int row0 = 64*qm + 16*mt;
                const unsigned ab = (unsigned)((row0 + arow)*256 + kgrp*16);
                #pragma unroll
                for (int kt = 0; kt < 4; ++kt) {    // h_before: hl rows s
                    const s16x8 av = *(const s16x8*)((const char*)hl + hlb + swz(ab + kt*64));
                    a0 = __builtin_amdgcn_mfma_f32_16x16x32_bf16(av, brg[0][kt], a0, 0, 0, 0);
                    a1 = __builtin_amdgcn_mfma_f32_16x16x32_bf16(av, brg[1][kt], a1, 0, 0, 0);
                    a2 = __builtin_amdgcn_mfma_f32_16x16x32_bf16(av, brg[2][kt], a2, 0, 0, 0);
                    a3 = __builtin_amdgcn_mfma_f32_16x16x32_bf16(av, brg[3][kt], a3, 0, 0, 0);
                }
                #pragma unroll
                for (int kt = 4; kt < 8; ++kt) {    // h: hl rows s+1
                    const s16x8 av = *(const s16x8*)((const char*)hl + hlb + swz(ab + 256 + (kt-4)*64));
                    a0 = __builtin_amdgcn_mfma_f32_16x16x32_bf16(av, brg[0][kt], a0, 0, 0, 0);
                    a1 = __builtin_amdgcn_mfma_f32_16x16x32_bf16(av, brg[1][kt], a1, 0, 0, 0);
                    a2 = __builtin_amdgcn_mfma_f32_16x16x32_bf16(av, brg[2][kt], a2, 0, 0, 0);
                    a3 = __builtin_amdgcn_mfma_f32_16x16x32_bf16(av, brg[3][kt], a3, 0, 0, 0);
                }
                #pragma unroll
                for (int kt = 8; kt < 12; ++kt) {   // h_after: hl rows s+2
                    const s16x8 av = *(const s16x8*)((const char*)hl + hlb + swz(ab + 512 + (kt-8)*64));
                    a0 = __builtin_amdgcn_mfma_f32_16x16x32_bf16(av, brg[0][kt], a0, 0, 0, 0);
                    a1 = __builtin_amdgcn_mfma_f32_16x16x32_bf16(av, brg[1][kt], a1, 0, 0, 0);
                    a2 = __builtin_amdgcn_mfma_f32_16x16x32_bf16(av, brg[2][kt], a2, 0, 0, 0);
                    a3 = __builtin_amdgcn_mfma_f32_16x16x32_bf16(av, brg[3][kt], a3, 0, 0, 0);
                }
                {   // kt12: [x0..x4, 1.0, 0...] -> x-part + bias
                    const s16x8 av = *(const s16x8*)((const char*)xlt + xlb +
                                                     (unsigned)((row0 + arow)*80 + kgrp*16));
                    a0 = __builtin_amdgcn_mfma_f32_16x16x32_bf16(av, brg[0][12], a0, 0, 0, 0);
                    a1 = __builtin_amdgcn_mfma_f32_16x16x32_bf16(av, brg[1][12], a1, 0, 0, 0);
                    a2 = __builtin_amdgcn_mfma_f32_16x16x32_bf16(av, brg[2][12], a2, 0, 0, 0);
                    a3 = __builtin_amdgcn_mfma_f32_16x16x32_bf16(av, brg[3][12], a3, 0, 0, 0);
                }
                #pragma unroll
                for (int r = 0; r < 4; ++r) {
                    const int row = row0 + kgrp*4 + r;
                    const float iv = a0[r], fv = a1[r], gv = a2[r], ov = a3[r];
                    const float si = __builtin_amdgcn_rcpf(1.f + __expf(-iv));
                    const float sf = __builtin_amdgcn_rcpf(1.f + __expf(-fv));
                    const float so = __builtin_amdgcn_rcpf(1.f + __expf(-ov));
                    const float tg = 1.f - 2.f*__builtin_amdgcn_rcpf(__expf(2.f*gv) + 1.f);
                    const float cn = sf*cst[mt*4 + r] + si*tg;
                    cst[mt*4 + r] = cn;
                    const float tc = 1.f - 2.f*__builtin_amdgcn_rcpf(__expf(2.f*cn) + 1.f);
                    const float hn = so*tc;
                    __hip_bfloat16 hbv = __float2bfloat16(hn);
                    *(unsigned short*)((char*)hl + nhlb +
                        swz((unsigned)((row + 1)*256 + (16*qh + arow)*2))) = *(unsigned short*)&hbv;
                }
            }
        }

        // ---- W1: relu(h(j) @ W1 + b1), wave = (mtD rows, qn col-half) ----
        if (j >= TPRED + 1) {
            f32x4 c0 = {0.f,0.f,0.f,0.f}, c1 = c0, c2 = c0, c3 = c0;
            const unsigned wb = (unsigned)((16*mtD + 1 + arow)*256 + kgrp*16);
            #pragma unroll
            for (int kt = 0; kt < 4; ++kt) {
                const s16x8 av = *(const s16x8*)((const char*)hl + hlb + swz(wb + kt*64));
                c0 = __builtin_amdgcn_mfma_f32_16x16x32_bf16(av, w1r[0][kt], c0, 0, 0, 0);
                c1 = __builtin_amdgcn_mfma_f32_16x16x32_bf16(av, w1r[1][kt], c1, 0, 0, 0);
                c2 = __builtin_amdgcn_mfma_f32_16x16x32_bf16(av, w1r[2][kt], c2, 0, 0, 0);
                c3 = __builtin_amdgcn_mfma_f32_16x16x32_bf16(av, w1r[3][kt], c3, 0, 0, 0);
            }
            #pragma unroll
            for (int nt = 0; nt < 4; ++nt) {
                const f32x4 cc = (nt == 0) ? c0 : (nt == 1) ? c1 : (nt == 2) ? c2 : c3;
                #pragma unroll
                for (int r = 0; r < 4; ++r) {
                    const int row = 16*mtD + kgrp*4 + r;
                    const int col = qn*64 + nt*16 + arow;
                    const float v = fmaxf(cc[r] + b1r[nt], 0.f);
                    __hip_bfloat16 bv = __float2bfloat16(v);
                    *(unsigned short*)((char*)relu_l +
                        swz((unsigned)(row*256 + col*2))) = *(unsigned short*)&bv;
                }
            }
        }
        BARRIER();  // B3: relu_l complete

        // ---- W2: out = relu @ W2 + b2 (N padded to 16), waves 0..7 ----
        if (j >= TPRED + 1 && q < 8) {
            f32x4 cc = {0.f,0.f,0.f,0.f};
            const unsigned wb2 = (unsigned)((16*q + arow)*256 + kgrp*16);
            #pragma unroll
            for (int kt = 0; kt < 4; ++kt) {
                const s16x8 av = *(const s16x8*)((const char*)relu_l + swz(wb2 + kt*64));
                cc = __builtin_amdgcn_mfma_f32_16x16x32_bf16(av, w2r[kt], cc, 0, 0, 0);
            }
            if (arow < 3) {
                #pragma unroll
                for (int r = 0; r < 4; ++r)
                    outl[(16*q + kgrp*4 + r)*3 + arow] = cc[r] + b2r;
            }
        }
        BARRIER();  // B4: outl complete

        // ---- epilogue: nd(j-1) rows 0..127 ----
        if (j >= TPRED + 1 && tid < 128) {
            const int m = tid;
            const int jm1_3 = (j - 1) % 3;
            const float no = outl[m*3 + 0];
            float In, sp0, sp1;
            if (m == 0) { In = xl[jm3][1]; sp0 = xl[jm3][3]; sp1 = xl[jm3][4]; }
            else { In = outl[(m - 1)*3 + 0]; sp0 = outl[m*3 + 1]; sp1 = outl[m*3 + 2]; }
            const float former = xl[jm1_3][m*5 + 2];
            const long base = ((long)(b*TOUT + (j - 1 - TPRED))*NS + m)*5;
            outp[base + 0] = no;
            outp[base + 1] = In;
            outp[base + 2] = former + In - no;
            outp[base + 3] = sp0;
            outp[base + 4] = sp1;
        }

        // ---- commit x(j+1) ----
        if (act640) xl[(j + 1) % 3][tid] = xr;
        if (act128) {
            __hip_bfloat16 c0 = __float2bfloat16(p0), c1 = __float2bfloat16(p1),
                           c2 = __float2bfloat16(p2), c3 = __float2bfloat16(p3),
                           c4 = __float2bfloat16(p4);
            unsigned short* xr0 = (unsigned short*)((char*)xlt +
                (unsigned)((j + 1) & 1)*10240u + tid*80);
            xr0[0] = *(unsigned short*)&c0; xr0[1] = *(unsigned short*)&c1;
            xr0[2] = *(unsigned short*)&c2; xr0[3] = *(unsigned short*)&c3;
            xr0[4] = *(unsigned short*)&c4; xr0[5] = 0x3F80; xr0[6] = 0; xr0[7] = 0;
        }
    }
}

extern "C" void kernel_launch(void* const* d_in, const int* in_sizes, int n_in,
                              void* d_out, int out_size, void* d_ws, size_t ws_size,
                              hipStream_t stream) {
    const float* input = (const float*)d_in[0];
    const float* Wc    = (const float*)d_in[1];
    const float* bc    = (const float*)d_in[2];
    const float* W1    = (const float*)d_in[3];
    const float* b1    = (const float*)d_in[4];
    const float* W2    = (const float*)d_in[5];
    const float* b2    = (const float*)d_in[6];
    float* outp = (float*)d_out;
    char* ws = (char*)d_ws;

    __hip_bfloat16* WTc = (__hip_bfloat16*)(ws + WS_WTC);
    __hip_bfloat16* WT1 = (__hip_bfloat16*)(ws + WS_WT1);
    __hip_bfloat16* WT2 = (__hip_bfloat16*)(ws + WS_WT2);

    init_weights<<<904, 256, 0, stream>>>(Wc, bc, W1, W2, WTc, WT1, WT2);
    lstm_persist<<<NB, 1024, 0, stream>>>(input, b1, b2, outp, WTc, WT1, WT2);
}

// Round 12
// 1415.224 us; speedup vs baseline: 7.3818x; 7.3818x over previous
//
#include <hip/hip_runtime.h>
#include <hip/hip_bf16.h>

// R12: temporal wedge blocking. 64 blocks = 8 batches x 8 chunks of 16 s-rows,
// each block carries an 8-row halo per side and advances 8 steps per exchange
// (sync cost /8). Exchange = 8 rows/side of {tag|h_bf16|c_f32} u64 words
// (self-validating, fire-and-forget). Uniform M=32 compute (wedge garbage is
// never read; halo refreshed each window). Weights: kt0..9 in regs (160),
// kt10..12 in LDS; x+bias folded in as kt12 (validated in R11).

#define NB 8
#define NT 128
#define NS 128
#define NSTEP 127
#define TPRED 4
#define TOUT 123

typedef __attribute__((ext_vector_type(4))) float f32x4;
typedef __attribute__((ext_vector_type(8))) short s16x8;
typedef __attribute__((ext_vector_type(4))) unsigned int u32x4;

// workspace layout (bytes)
#define WS_WTC 0                          // bf16 [512][416] col''=q*64+g*16+h; K=[hb,h,ha,x,1,pad]
#define WS_WT1 (512*416*2)                // bf16 [128][128] [out_col][k]
#define WS_HCP (WS_WT1 + 128*128*2)       // u64 [2 par][8 b][8 c][2 side][8 row][128 col]
#define WS_HCP_BYTES (2*8*8*2*8*128*8)    // 2 MB

#define BARRIER() do { \
    __builtin_amdgcn_sched_barrier(0); \
    asm volatile("s_waitcnt lgkmcnt(0)" ::: "memory"); \
    __builtin_amdgcn_s_barrier(); \
    __builtin_amdgcn_sched_barrier(0); \
} while (0)

__device__ __forceinline__ unsigned swz(unsigned off) {
    return off ^ (((off >> 8) & 7u) << 4);
}

__global__ void init_weights(const float* __restrict__ Wc, const float* __restrict__ bc,
                             const float* __restrict__ W1,
                             __hip_bfloat16* __restrict__ WTc, __hip_bfloat16* __restrict__ WT1)
{
    int i = blockIdx.x * blockDim.x + threadIdx.x;
    if (i < 512*416) {
        int cpp = i / 416, k = i % 416;
        int q = cpp >> 6, rem = cpp & 63, g = rem >> 4, h = rem & 15;
        int oc = g*128 + 16*q + h;     // original W_cell column
        float v;
        if      (k < 128) v = Wc[(261 + k)*512 + oc];          // h_before
        else if (k < 256) v = Wc[(5 + (k - 128))*512 + oc];    // h
        else if (k < 384) v = Wc[(133 + (k - 256))*512 + oc];  // h_after
        else if (k < 389) v = Wc[(k - 384)*512 + oc];          // x0..x4
        else if (k == 389) v = bc[oc];                          // bias (x1.0)
        else v = 0.f;
        WTc[cpp*416 + k] = __float2bfloat16(v);
    } else if (i < 512*416 + 128*128) {
        int qq = i - 512*416;
        int nn = qq >> 7, k = qq & 127;
        WT1[nn*128 + k] = __float2bfloat16(W1[k*128 + nn]);
    }
}

__global__ __launch_bounds__(512, 1) void lstm_persist(
    const float* __restrict__ input, const float* __restrict__ b1v,
    const float* __restrict__ W2, const float* __restrict__ b2,
    float* __restrict__ outp,
    const __hip_bfloat16* __restrict__ WTc, const __hip_bfloat16* __restrict__ WT1,
    unsigned long long* hcpub)
{
    // hl rows: lrow = g - s0 + 9, g in [s0-9, s0+24]; lrow 0/33 permanently zero
    __shared__ __align__(16) __hip_bfloat16 hl[2*34*128];     // 17,408 B (swz, 256B rows)
    __shared__ __align__(16) __hip_bfloat16 bl[512*104];      // kt10..12 B-frags: [col''][208B]
    __shared__ __align__(16) __hip_bfloat16 relu_l[18*128];   // swz, rows 0..16
    __shared__ __align__(16) __hip_bfloat16 xlt[2*32*40];     // [par][32 rows][40]: x0..4,1.0,0...
    __shared__ float xl[3][80];     // f32 x, owned rows, mod-3
    __shared__ float outl[17*3];    // wave-0 private
    __shared__ float w2l[3*128];
    __shared__ float b2l[3];

    const int tid  = threadIdx.x;
    const int blk  = blockIdx.x;
    const int b    = blk & 7;       // batch
    const int c    = blk >> 3;      // s-chunk: owned rows [16c, 16c+16)
    const int s0   = 16*c;
    const int lane = tid & 63;
    const int q    = tid >> 6;      // wave 0..7 = hid group
    const int arow = lane & 15;
    const int kgrp = lane >> 4;
    const int hidw = 16*q + arow;   // hid col this lane owns

    for (int i = tid; i < 2*34*128; i += 512) ((unsigned short*)hl)[i] = 0;
    for (int i = tid; i < 2*32*40; i += 512) ((unsigned short*)xlt)[i] = 0;
    if (tid < 384) w2l[tid] = W2[(tid & 127)*3 + (tid >> 7)];
    if (tid >= 384 && tid < 387) b2l[tid - 384] = b2[tid - 384];
    // stage bl: kt10..12 for all 512 cols (3 x 32 bf16 per col, stride 208B)
    for (int i = tid; i < 512*24; i += 512) {
        const int col = i / 24, r8 = i % 24;
        const int kt = 10 + (r8 >> 3), sub = r8 & 7;
        *(unsigned long long*)((char*)bl + col*208 + (kt - 10)*64 + sub*8) =
            *(const unsigned long long*)((const char*)WTc + ((unsigned)col*416 + kt*32 + sub*4)*2);
    }
    // stage x(0)
    if (tid < 80) xl[0][tid] = input[((unsigned)(b*NT)*NS + s0)*5 + tid];
    if (tid < 32) {
        int g = s0 - 8 + tid; g = g < 0 ? 0 : (g > 127 ? 127 : g);
        const float* xp = input + ((unsigned)(b*NT)*NS + g)*5;
        unsigned short* xr0 = (unsigned short*)((char*)xlt + tid*80);
        __hip_bfloat16 v0 = __float2bfloat16(xp[0]), v1 = __float2bfloat16(xp[1]),
                       v2 = __float2bfloat16(xp[2]), v3 = __float2bfloat16(xp[3]),
                       v4 = __float2bfloat16(xp[4]);
        xr0[0] = *(unsigned short*)&v0; xr0[1] = *(unsigned short*)&v1;
        xr0[2] = *(unsigned short*)&v2; xr0[3] = *(unsigned short*)&v3;
        xr0[4] = *(unsigned short*)&v4; xr0[5] = 0x3F80;
    }

    // register weights: kt0..9
    s16x8 brg[4][10];
    #pragma unroll
    for (int g = 0; g < 4; ++g)
        #pragma unroll
        for (int kt = 0; kt < 10; ++kt)
            brg[g][kt] = *(const s16x8*)((const char*)WTc +
                ((unsigned)(q*64 + g*16 + arow)*416 + kt*32 + kgrp*8)*2);
    s16x8 w1r[4];
    #pragma unroll
    for (int kt = 0; kt < 4; ++kt)
        w1r[kt] = *(const s16x8*)((const char*)WT1 + ((unsigned)hidw*128 + kt*32 + kgrp*8)*2);
    const float b1r = b1v[hidw];

    float cst[8];                    // c: [mt]: rows s0-8+mt*16+kgrp*4+r, col hidw
    #pragma unroll
    for (int i = 0; i < 8; ++i) cst[i] = 0.f;

    __syncthreads();

    for (int j = 0; j <= NSTEP; ++j) {
        const int jm3 = j % 3;
        const unsigned hlb  = (unsigned)(j & 1) * 8704u;          // 34*256
        const unsigned nhlb = (unsigned)((j + 1) & 1) * 8704u;
        const unsigned xlb  = (unsigned)(j & 1) * 2560u;          // 32*80

        // ---- prefetch x(j+1) ----
        float xr = 0.f, p0 = 0.f, p1 = 0.f, p2 = 0.f, p3 = 0.f, p4 = 0.f;
        const bool act80 = (j < NSTEP) && (tid < 80);
        const bool act32 = (j < NSTEP) && (tid < 32);
        if (act80) xr = input[((unsigned)(b*NT + j + 1)*NS + s0)*5 + tid];
        if (act32) {
            int g = s0 - 8 + tid; g = g < 0 ? 0 : (g > 127 ? 127 : g);
            const float* xp = input + ((unsigned)(b*NT + j + 1)*NS + g)*5;
            p0 = xp[0]; p1 = xp[1]; p2 = xp[2]; p3 = xp[3]; p4 = xp[4];
        }

        // ---- window start: gather 8-row halos of h(j),c(j) ----
        const bool isgather = (j > 0) && ((j & 7) == 0);
        if (isgather) {
            const unsigned wtag = (unsigned)(j >> 3);
            const unsigned par  = wtag & 1;
            const int side = tid >> 8;          // 0=left halo, 1=right halo
            const int i2   = tid & 255;
            const bool act = (side == 0) ? (c > 0) : (c < 7);
            if (act) {
                const int nc = (side == 0) ? c - 1 : c + 1;
                const int ns = 1 - side;        // left halo <- neighbor's high, right <- low
                const unsigned long long* qp =
                    hcpub + (unsigned)((((par*8 + b)*8 + nc)*2 + ns)*1024 + i2*4);
                u32x4 ga, gb;
                for (;;) {
                    asm volatile(
                        "global_load_dwordx4 %0, %2, off sc0 sc1\n\t"
                        "global_load_dwordx4 %1, %3, off sc0 sc1\n\t"
                        "s_waitcnt vmcnt(0)"
                        : "=&v"(ga), "=&v"(gb)
                        : "v"(qp), "v"(qp + 2) : "memory");
                    if ((ga[1] >> 16) == wtag && (ga[3] >> 16) == wtag &&
                        (gb[1] >> 16) == wtag && (gb[3] >> 16) == wtag) break;
                }
                __builtin_amdgcn_sched_barrier(0);
                const int row = i2 >> 5, col0 = (i2 & 31)*4;
                const int lr = (side == 0) ? 1 + row : 25 + row;
                const unsigned long long pk =
                    (unsigned long long)(ga[1] & 0xffffu)
                  | ((unsigned long long)(ga[3] & 0xffffu) << 16)
                  | ((unsigned long long)(gb[1] & 0xffffu) << 32)
                  | ((unsigned long long)(gb[3] & 0xffffu) << 48);
                *(unsigned long long*)((char*)hl + hlb + swz((unsigned)(lr*256 + col0*2))) = pk;
            }
            BARRIER();   // tags seen by gatherers -> all words visible; halo in LDS
            // c halo -> registers (c was packed in the same u64 words)
            if (c > 0 && kgrp < 2) {           // mt0 halo rows s0-8+kgrp*4+r
                const unsigned long long* cp =
                    hcpub + (unsigned)((((par*8 + b)*8 + (c - 1))*2 + 1)*1024 + (kgrp*4)*128 + hidw);
                unsigned long long v0, v1, v2, v3;
                asm volatile(
                    "global_load_dwordx2 %0, %4, off sc0 sc1\n\t"
                    "global_load_dwordx2 %1, %5, off sc0 sc1\n\t"
                    "global_load_dwordx2 %2, %6, off sc0 sc1\n\t"
                    "global_load_dwordx2 %3, %7, off sc0 sc1\n\t"
                    "s_waitcnt vmcnt(0)"
                    : "=&v"(v0), "=&v"(v1), "=&v"(v2), "=&v"(v3)
                    : "v"(cp), "v"(cp + 128), "v"(cp + 256), "v"(cp + 384) : "memory");
                cst[0] = __uint_as_float((unsigned)v0);
                cst[1] = __uint_as_float((unsigned)v1);
                cst[2] = __uint_as_float((unsigned)v2);
                cst[3] = __uint_as_float((unsigned)v3);
            }
            if (c < 7 && kgrp >= 2) {          // mt1 halo rows s0+16+(kgrp-2)*4+r
                const unsigned long long* cp =
                    hcpub + (unsigned)((((par*8 + b)*8 + (c + 1))*2 + 0)*1024 + ((kgrp - 2)*4)*128 + hidw);
                unsigned long long v0, v1, v2, v3;
                asm volatile(
                    "global_load_dwordx2 %0, %4, off sc0 sc1\n\t"
                    "global_load_dwordx2 %1, %5, off sc0 sc1\n\t"
                    "global_load_dwordx2 %2, %6, off sc0 sc1\n\t"
                    "global_load_dwordx2 %3, %7, off sc0 sc1\n\t"
                    "s_waitcnt vmcnt(0)"
                    : "=&v"(v0), "=&v"(v1), "=&v"(v2), "=&v"(v3)
                    : "v"(cp), "v"(cp + 128), "v"(cp + 256), "v"(cp + 384) : "memory");
                cst[4] = __uint_as_float((unsigned)v0);
                cst[5] = __uint_as_float((unsigned)v1);
                cst[6] = __uint_as_float((unsigned)v2);
                cst[7] = __uint_as_float((unsigned)v3);
            }
        }
        BARRIER();  // B1: hl[j&1] (h(j)) ready, xlt/xl staged

        // ---- z-phase: M=32 (2 tiles) N=512 K=416 + gates -> h(j+1) ----
        if (j < NSTEP) {
            const bool PUB = ((j + 1) & 7) == 0;    // publish h(j+1),c(j+1) owned rows
            const unsigned wtag1 = (unsigned)((j + 1) >> 3);
            unsigned hsv[4], csv[4];
            #pragma unroll
            for (int mt = 0; mt < 2; ++mt) {
                f32x4 a0 = {0.f,0.f,0.f,0.f}, a1 = a0, a2 = a0, a3 = a0;
                const unsigned ab = (unsigned)((mt*16 + arow)*256 + kgrp*16);
                #pragma unroll
                for (int kt = 0; kt < 4; ++kt) {      // h_before
                    const s16x8 av = *(const s16x8*)((const char*)hl + hlb + swz(ab + kt*64));
                    a0 = __builtin_amdgcn_mfma_f32_16x16x32_bf16(av, brg[0][kt], a0, 0, 0, 0);
                    a1 = __builtin_amdgcn_mfma_f32_16x16x32_bf16(av, brg[1][kt], a1, 0, 0, 0);
                    a2 = __builtin_amdgcn_mfma_f32_16x16x32_bf16(av, brg[2][kt], a2, 0, 0, 0);
                    a3 = __builtin_amdgcn_mfma_f32_16x16x32_bf16(av, brg[3][kt], a3, 0, 0, 0);
                }
                #pragma unroll
                for (int kt = 4; kt < 8; ++kt) {      // h
                    const s16x8 av = *(const s16x8*)((const char*)hl + hlb + swz(ab + 256 + (kt-4)*64));
                    a0 = __builtin_amdgcn_mfma_f32_16x16x32_bf16(av, brg[0][kt], a0, 0, 0, 0);
                    a1 = __builtin_amdgcn_mfma_f32_16x16x32_bf16(av, brg[1][kt], a1, 0, 0, 0);
                    a2 = __builtin_amdgcn_mfma_f32_16x16x32_bf16(av, brg[2][kt], a2, 0, 0, 0);
                    a3 = __builtin_amdgcn_mfma_f32_16x16x32_bf16(av, brg[3][kt], a3, 0, 0, 0);
                }
                #pragma unroll
                for (int kt = 8; kt < 10; ++kt) {     // h_after (reg B)
                    const s16x8 av = *(const s16x8*)((const char*)hl + hlb + swz(ab + 512 + (kt-8)*64));
                    a0 = __builtin_amdgcn_mfma_f32_16x16x32_bf16(av, brg[0][kt], a0, 0, 0, 0);
                    a1 = __builtin_amdgcn_mfma_f32_16x16x32_bf16(av, brg[1][kt], a1, 0, 0, 0);
                    a2 = __builtin_amdgcn_mfma_f32_16x16x32_bf16(av, brg[2][kt], a2, 0, 0, 0);
                    a3 = __builtin_amdgcn_mfma_f32_16x16x32_bf16(av, brg[3][kt], a3, 0, 0, 0);
                }
                #pragma unroll
                for (int kt = 10; kt < 12; ++kt) {    // h_after (LDS B)
                    const s16x8 av = *(const s16x8*)((const char*)hl + hlb + swz(ab + 512 + (kt-8)*64));
                    const char* blb = (const char*)bl + (kt - 10)*64 + kgrp*16;
                    a0 = __builtin_amdgcn_mfma_f32_16x16x32_bf16(av, *(const s16x8*)(blb + (q*64 + 0*16 + arow)*208), a0, 0, 0, 0);
                    a1 = __builtin_amdgcn_mfma_f32_16x16x32_bf16(av, *(const s16x8*)(blb + (q*64 + 1*16 + arow)*208), a1, 0, 0, 0);
                    a2 = __builtin_amdgcn_mfma_f32_16x16x32_bf16(av, *(const s16x8*)(blb + (q*64 + 2*16 + arow)*208), a2, 0, 0, 0);
                    a3 = __builtin_amdgcn_mfma_f32_16x16x32_bf16(av, *(const s16x8*)(blb + (q*64 + 3*16 + arow)*208), a3, 0, 0, 0);
                }
                {   // kt12: x + bias
                    const s16x8 av = *(const s16x8*)((const char*)xlt + xlb +
                                                     (unsigned)((mt*16 + arow)*80 + kgrp*16));
                    const char* blb = (const char*)bl + 128 + kgrp*16;
                    a0 = __builtin_amdgcn_mfma_f32_16x16x32_bf16(av, *(const s16x8*)(blb + (q*64 + 0*16 + arow)*208), a0, 0, 0, 0);
                    a1 = __builtin_amdgcn_mfma_f32_16x16x32_bf16(av, *(const s16x8*)(blb + (q*64 + 1*16 + arow)*208), a1, 0, 0, 0);
                    a2 = __builtin_amdgcn_mfma_f32_16x16x32_bf16(av, *(const s16x8*)(blb + (q*64 + 2*16 + arow)*208), a2, 0, 0, 0);
                    a3 = __builtin_amdgcn_mfma_f32_16x16x32_bf16(av, *(const s16x8*)(blb + (q*64 + 3*16 + arow)*208), a3, 0, 0, 0);
                }
                #pragma unroll
                for (int r = 0; r < 4; ++r) {
                    const int trow = mt*16 + kgrp*4 + r;       // 0..31
                    const int g    = s0 - 8 + trow;            // global s-row
                    const float si = __builtin_amdgcn_rcpf(1.f + __expf(-a0[r]));
                    const float sf = __builtin_amdgcn_rcpf(1.f + __expf(-a1[r]));
                    const float so = __builtin_amdgcn_rcpf(1.f + __expf(-a3[r]));
                    const float tg = 1.f - 2.f*__builtin_amdgcn_rcpf(__expf(2.f*a2[r]) + 1.f);
                    const float cn = sf*cst[mt*4 + r] + si*tg;
                    cst[mt*4 + r] = cn;
                    const float tc = 1.f - 2.f*__builtin_amdgcn_rcpf(__expf(2.f*cn) + 1.f);
                    const float hn = so*tc;
                    __hip_bfloat16 hbv = __float2bfloat16(hn);
                    const unsigned short hbits = *(const unsigned short*)&hbv;
                    if ((unsigned)g < 128u)
                        *(unsigned short*)((char*)hl + nhlb +
                            swz((unsigned)((trow + 1)*256 + hidw*2))) = hbits;
                    if (PUB && ((mt == 0) == (kgrp >= 2))) {   // owned rows only
                        hsv[r] = (unsigned)hbits;
                        csv[r] = __float_as_uint(cn);
                    }
                }
            }
            if (PUB) {
                const unsigned par1 = wtag1 & 1;
                const int side  = (kgrp >= 2) ? 0 : 1;         // low rows / high rows
                const int prow0 = (kgrp >= 2) ? (kgrp - 2)*4 : kgrp*4;
                unsigned long long* pb =
                    hcpub + (unsigned)((((par1*8 + b)*8 + c)*2 + side)*1024 + hidw);
                #pragma unroll
                for (int r = 0; r < 4; ++r) {
                    const unsigned long long word =
                        ((unsigned long long)wtag1 << 48)
                      | ((unsigned long long)hsv[r] << 32)
                      | (unsigned long long)csv[r];
                    asm volatile("global_store_dwordx2 %0, %1, off sc0 sc1"
                                 :: "v"(pb + (prow0 + r)*128), "v"(word) : "memory");
                }
                // fire-and-forget: readers poll the tags
            }
        }

        // ---- D: out(j-1) from h(j), rows s0-1..s0+15 (lrow 8..24) ----
        if (j >= TPRED + 1) {
            const int jm1_3 = (j - 1) % 3;
            f32x4 c0 = {0.f,0.f,0.f,0.f}, c1 = c0;
            const unsigned w1a = (unsigned)((8 + arow)*256 + kgrp*16);
            #pragma unroll
            for (int kt = 0; kt < 4; ++kt) {
                const s16x8 av0 = *(const s16x8*)((const char*)hl + hlb + swz(w1a + kt*64));
                const s16x8 av1 = *(const s16x8*)((const char*)hl + hlb + swz(w1a + 256 + kt*64));
                c0 = __builtin_amdgcn_mfma_f32_16x16x32_bf16(av0, w1r[kt], c0, 0, 0, 0);
                c1 = __builtin_amdgcn_mfma_f32_16x16x32_bf16(av1, w1r[kt], c1, 0, 0, 0);
            }
            #pragma unroll
            for (int r = 0; r < 4; ++r) {
                const int lr = kgrp*4 + r;
                const float v0 = fmaxf(c0[r] + b1r, 0.f);
                *(__hip_bfloat16*)((char*)relu_l + swz((unsigned)(lr*256 + hidw*2))) = __float2bfloat16(v0);
                if (lr == 15) {
                    const float v1 = fmaxf(c1[r] + b1r, 0.f);
                    *(__hip_bfloat16*)((char*)relu_l + swz((unsigned)(16*256 + hidw*2))) = __float2bfloat16(v1);
                }
            }
            BARRIER();  // B3 (j block-uniform)
            if (tid < 51) {
                const int m = tid / 3, p = tid - m*3;
                float s = b2l[p];
                #pragma unroll
                for (int kc = 0; kc < 16; ++kc) {
                    union { s16x8 v; unsigned short u[8]; } uu;
                    uu.v = *(const s16x8*)((const char*)relu_l + swz((unsigned)(m*256 + kc*16)));
                    #pragma unroll
                    for (int e = 0; e < 8; ++e)
                        s += __uint_as_float((unsigned)uu.u[e] << 16) * w2l[p*128 + kc*8 + e];
                }
                outl[m*3 + p] = s;   // out row s0-1+m
            }
            // outl: wave-0 write then wave-0 read -> in-order
            if (tid < 16) {
                const int m = tid, grow = s0 + m;
                const float no = outl[(m + 1)*3 + 0];
                float In, sp0, sp1;
                if (m == 0 && c == 0) { In = xl[jm3][1]; sp0 = xl[jm3][3]; sp1 = xl[jm3][4]; }
                else { In = outl[m*3 + 0]; sp0 = outl[(m + 1)*3 + 1]; sp1 = outl[(m + 1)*3 + 2]; }
                const float former = xl[jm1_3][m*5 + 2];
                const long base = ((long)(b*TOUT + (j - 1 - TPRED))*NS + grow)*5;
                outp[base + 0] = no;
                outp[base + 1] = In;
                outp[base + 2] = former + In - no;
                outp[base + 3] = sp0;
                outp[base + 4] = sp1;
            }
        }

        // ---- commit x(j+1) ----
        if (act80) xl[(j + 1) % 3][tid] = xr;
        if (act32) {
            __hip_bfloat16 v0 = __float2bfloat16(p0), v1 = __float2bfloat16(p1),
                           v2 = __float2bfloat16(p2), v3 = __float2bfloat16(p3),
                           v4 = __float2bfloat16(p4);
            unsigned short* xr0 = (unsigned short*)((char*)xlt +
                (unsigned)((j + 1) & 1)*2560u + tid*80);
            xr0[0] = *(unsigned short*)&v0; xr0[1] = *(unsigned short*)&v1;
            xr0[2] = *(unsigned short*)&v2; xr0[3] = *(unsigned short*)&v3;
            xr0[4] = *(unsigned short*)&v4; xr0[5] = 0x3F80;
        }
    }
}

extern "C" void kernel_launch(void* const* d_in, const int* in_sizes, int n_in,
                              void* d_out, int out_size, void* d_ws, size_t ws_size,
                              hipStream_t stream) {
    const float* input = (const float*)d_in[0];
    const float* Wc    = (const float*)d_in[1];
    const float* bc    = (const float*)d_in[2];
    const float* W1    = (const float*)d_in[3];
    const float* b1    = (const float*)d_in[4];
    const float* W2    = (const float*)d_in[5];
    const float* b2    = (const float*)d_in[6];
    float* outp = (float*)d_out;
    char* ws = (char*)d_ws;

    __hip_bfloat16* WTc = (__hip_bfloat16*)(ws + WS_WTC);
    __hip_bfloat16* WT1 = (__hip_bfloat16*)(ws + WS_WT1);
    unsigned long long* hcp = (unsigned long long*)(ws + WS_HCP);

    hipMemsetAsync(ws + WS_HCP, 0, WS_HCP_BYTES, stream);   // tags=0: never match w>=1
    init_weights<<<896, 256, 0, stream>>>(Wc, bc, W1, WTc, WT1);
    lstm_persist<<<64, 512, 0, stream>>>(input, b1, W2, b2, outp, WTc, WT1, hcp);
}